// Round 7
// baseline (300.609 us; speedup 1.0000x reference)
//
#include <hip/hip_runtime.h>
#include <math.h>

#define B_   32
#define N_   128
#define H_   100
#define NW   4            // rows (waves) per block
#define ROWS (B_ * N_)    // 4096
#define RH   (ROWS * H_)  // 409600

// ---------------------------------------------------------------------------
// K1: hv = nodes@Wv, hw = nodes@Ww. One wave per row; lane l -> h = 2l, 2l+1.
__global__ __launch_bounds__(256, 4) void k_proj0(const float* __restrict__ nodes,
                                                  const float* __restrict__ Wv,
                                                  const float* __restrict__ Ww,
                                                  float* __restrict__ hv,
                                                  float* __restrict__ hw) {
    __shared__ float nod_s[NW][H_];
    const int t = threadIdx.x, wv = t >> 6, l = t & 63;
    const int row = blockIdx.x * NW + wv;
    {
        const float4* ng = (const float4*)(nodes + (size_t)row * H_);
        if (l < 25) ((float4*)nod_s[wv])[l] = ng[l];
    }
    __syncthreads();
    if (l >= 50) return;
    const float2* Wv2 = (const float2*)Wv;   // [100][50] float2
    const float2* Ww2 = (const float2*)Ww;
    const float4* h4p = (const float4*)nod_s[wv];
    float va0 = 0, va1 = 0, wa0 = 0, wa1 = 0;
#pragma unroll 5
    for (int k4 = 0; k4 < 25; ++k4) {
        const float4 h4 = h4p[k4];
        const int k = 4 * k4;
        const float2 v0 = Wv2[(k + 0) * 50 + l], w0 = Ww2[(k + 0) * 50 + l];
        const float2 v1 = Wv2[(k + 1) * 50 + l], w1 = Ww2[(k + 1) * 50 + l];
        const float2 v2 = Wv2[(k + 2) * 50 + l], w2 = Ww2[(k + 2) * 50 + l];
        const float2 v3 = Wv2[(k + 3) * 50 + l], w3 = Ww2[(k + 3) * 50 + l];
        va0 = fmaf(h4.x, v0.x, va0); va1 = fmaf(h4.x, v0.y, va1);
        wa0 = fmaf(h4.x, w0.x, wa0); wa1 = fmaf(h4.x, w0.y, wa1);
        va0 = fmaf(h4.y, v1.x, va0); va1 = fmaf(h4.y, v1.y, va1);
        wa0 = fmaf(h4.y, w1.x, wa0); wa1 = fmaf(h4.y, w1.y, wa1);
        va0 = fmaf(h4.z, v2.x, va0); va1 = fmaf(h4.z, v2.y, va1);
        wa0 = fmaf(h4.z, w2.x, wa0); wa1 = fmaf(h4.z, w2.y, wa1);
        va0 = fmaf(h4.w, v3.x, va0); va1 = fmaf(h4.w, v3.y, va1);
        wa0 = fmaf(h4.w, w3.x, wa0); wa1 = fmaf(h4.w, w3.y, wa1);
    }
    *(float2*)(hv + (size_t)row * H_ + 2 * l) = make_float2(va0, va1);
    *(float2*)(hw + (size_t)row * H_ + 2 * l) = make_float2(wa0, wa1);
}

// ---------------------------------------------------------------------------
// K2: one fused message pass. One wave per row; lane l -> h = 2l, 2l+1.
// Message loop: e from LDS (b128 broadcast), hw coalesced float2 from global,
// mask + node-mask recomputed in VALU (exact: edges >= 0). Then tanh update;
// mode 1 -> next-pass hv/hw projections; mode 2 -> fused readout.
__global__ __launch_bounds__(256, 4) void k_pass(const float* __restrict__ edges,
                                                 const float* __restrict__ We,
                                                 const float* __restrict__ Wu,
                                                 const float* __restrict__ Wv,
                                                 const float* __restrict__ Ww,
                                                 const float* __restrict__ Wr,
                                                 const float* __restrict__ nodes,
                                                 float* __restrict__ hv_io,
                                                 const float* __restrict__ hw_in,
                                                 float* __restrict__ hw_out,
                                                 const float* __restrict__ hid_in,
                                                 float* __restrict__ hidden,
                                                 float* __restrict__ out,
                                                 int mode) {
    __shared__ float4 e_s[NW][N_];     // 8 KB
    __shared__ float  hid_s[NW][H_];
    __shared__ float  msg_s[NW][H_];
    __shared__ float  hn_s[NW][H_];
    __shared__ float  nod_s[NW][H_];   // mode 2 only

    const int t = threadIdx.x, wv = t >> 6, l = t & 63;
    const int row = blockIdx.x * NW + wv;
    const int b = row >> 7;
    const bool act = (l < 50);

    {   // stage own row's edges (2 coalesced float4 loads) + hidden (+nodes)
        const float4* eg = (const float4*)(edges + (size_t)row * N_ * 4);
        e_s[wv][l]      = eg[l];
        e_s[wv][l + 64] = eg[l + 64];
        const float4* hg = (const float4*)(hid_in + (size_t)row * H_);
        if (l < 25) ((float4*)hid_s[wv])[l] = hg[l];
        if (mode == 2 && l < 25)
            ((float4*)nod_s[wv])[l] = ((const float4*)(nodes + (size_t)row * H_))[l];
    }
    __syncthreads();

    float asum = 0.f;
    if (act) {
        const float2 hv2 = *(const float2*)(hv_io + (size_t)row * H_ + 2 * l);
        const float2 we0 = *(const float2*)(We + 0 * H_ + 2 * l);
        const float2 we1 = *(const float2*)(We + 1 * H_ + 2 * l);
        const float2 we2 = *(const float2*)(We + 2 * H_ + 2 * l);
        const float2 we3 = *(const float2*)(We + 3 * H_ + 2 * l);
        const float* hwp = hw_in + (size_t)b * N_ * H_ + 2 * l;
        float acc0 = 0.f, acc1 = 0.f;
#pragma unroll 8
        for (int w = 0; w < N_; ++w) {
            const float4 e = e_s[wv][w];                    // LDS broadcast
            const float2 hw2 = *(const float2*)(hwp + w * H_);  // coalesced
            const float s = (e.x + e.y) + (e.z + e.w);
            const float m = (s != 0.f) ? 1.f : 0.f;
            asum += s;
            float p0 = hv2.x + hw2.x, p1 = hv2.y + hw2.y;
            p0 = fmaf(e.x, we0.x, p0); p1 = fmaf(e.x, we0.y, p1);
            p0 = fmaf(e.y, we1.x, p0); p1 = fmaf(e.y, we1.y, p1);
            p0 = fmaf(e.z, we2.x, p0); p1 = fmaf(e.z, we2.y, p1);
            p0 = fmaf(e.w, we3.x, p0); p1 = fmaf(e.w, we3.y, p1);
            acc0 = fmaf(m, fmaxf(p0, 0.f), acc0);
            acc1 = fmaf(m, fmaxf(p1, 0.f), acc1);
        }
        *(float2*)(&msg_s[wv][2 * l]) = make_float2(acc0, acc1);
    }
    __syncthreads();

    // update: u = [hid, msg] @ Wu ; nh = nmask ? tanh(u) : hid
    float nh0 = 0.f, nh1 = 0.f;
    const float nm = (asum != 0.f) ? 1.f : 0.f;   // uniform across active lanes
    if (act) {
        const float2* Wu2 = (const float2*)Wu;    // [200][50] float2
        const float4* h4p = (const float4*)hid_s[wv];
        const float4* m4p = (const float4*)msg_s[wv];
        float u0 = 0.f, u1 = 0.f;
#pragma unroll 5
        for (int k4 = 0; k4 < 25; ++k4) {
            const float4 h4 = h4p[k4];
            const int k = 4 * k4;
            const float2 a = Wu2[(k + 0) * 50 + l];
            const float2 c = Wu2[(k + 1) * 50 + l];
            const float2 d = Wu2[(k + 2) * 50 + l];
            const float2 e = Wu2[(k + 3) * 50 + l];
            u0 = fmaf(h4.x, a.x, u0); u1 = fmaf(h4.x, a.y, u1);
            u0 = fmaf(h4.y, c.x, u0); u1 = fmaf(h4.y, c.y, u1);
            u0 = fmaf(h4.z, d.x, u0); u1 = fmaf(h4.z, d.y, u1);
            u0 = fmaf(h4.w, e.x, u0); u1 = fmaf(h4.w, e.y, u1);
        }
#pragma unroll 5
        for (int k4 = 0; k4 < 25; ++k4) {
            const float4 m4 = m4p[k4];
            const int k = H_ + 4 * k4;
            const float2 a = Wu2[(k + 0) * 50 + l];
            const float2 c = Wu2[(k + 1) * 50 + l];
            const float2 d = Wu2[(k + 2) * 50 + l];
            const float2 e = Wu2[(k + 3) * 50 + l];
            u0 = fmaf(m4.x, a.x, u0); u1 = fmaf(m4.x, a.y, u1);
            u0 = fmaf(m4.y, c.x, u0); u1 = fmaf(m4.y, c.y, u1);
            u0 = fmaf(m4.z, d.x, u0); u1 = fmaf(m4.z, d.y, u1);
            u0 = fmaf(m4.w, e.x, u0); u1 = fmaf(m4.w, e.y, u1);
        }
        nh0 = (nm != 0.f) ? tanhf(u0) : hid_s[wv][2 * l];
        nh1 = (nm != 0.f) ? tanhf(u1) : hid_s[wv][2 * l + 1];
        *(float2*)(&hn_s[wv][2 * l]) = make_float2(nh0, nh1);
        if (mode == 1)
            *(float2*)(hidden + (size_t)row * H_ + 2 * l) = make_float2(nh0, nh1);
    }
    __syncthreads();

    if (mode == 1) {    // next pass's hv/hw from fresh hidden (own row)
        if (act) {
            const float2* Wv2 = (const float2*)Wv;
            const float2* Ww2 = (const float2*)Ww;
            const float4* h4p = (const float4*)hn_s[wv];
            float va0 = 0, va1 = 0, wa0 = 0, wa1 = 0;
#pragma unroll 5
            for (int k4 = 0; k4 < 25; ++k4) {
                const float4 h4 = h4p[k4];
                const int k = 4 * k4;
                const float2 v0 = Wv2[(k + 0) * 50 + l], w0 = Ww2[(k + 0) * 50 + l];
                const float2 v1 = Wv2[(k + 1) * 50 + l], w1 = Ww2[(k + 1) * 50 + l];
                const float2 v2 = Wv2[(k + 2) * 50 + l], w2 = Ww2[(k + 2) * 50 + l];
                const float2 v3 = Wv2[(k + 3) * 50 + l], w3 = Ww2[(k + 3) * 50 + l];
                va0 = fmaf(h4.x, v0.x, va0); va1 = fmaf(h4.x, v0.y, va1);
                wa0 = fmaf(h4.x, w0.x, wa0); wa1 = fmaf(h4.x, w0.y, wa1);
                va0 = fmaf(h4.y, v1.x, va0); va1 = fmaf(h4.y, v1.y, va1);
                wa0 = fmaf(h4.y, w1.x, wa0); wa1 = fmaf(h4.y, w1.y, wa1);
                va0 = fmaf(h4.z, v2.x, va0); va1 = fmaf(h4.z, v2.y, va1);
                wa0 = fmaf(h4.z, w2.x, wa0); wa1 = fmaf(h4.z, w2.y, wa1);
                va0 = fmaf(h4.w, v3.x, va0); va1 = fmaf(h4.w, v3.y, va1);
                wa0 = fmaf(h4.w, w3.x, wa0); wa1 = fmaf(h4.w, w3.y, wa1);
            }
            *(float2*)(hv_io + (size_t)row * H_ + 2 * l) = make_float2(va0, va1);
            *(float2*)(hw_out + (size_t)row * H_ + 2 * l) = make_float2(wa0, wa1);
        }
    } else {            // mode 2: fused readout, per-wave atomics
        if (act) {
            const float2* Wr2 = (const float2*)Wr;
            const float4* h4p = (const float4*)hn_s[wv];
            const float4* n4p = (const float4*)nod_s[wv];
            float u0 = 0.f, u1 = 0.f;
#pragma unroll 5
            for (int k4 = 0; k4 < 25; ++k4) {
                const float4 h4 = h4p[k4];
                const int k = 4 * k4;
                const float2 a = Wr2[(k + 0) * 50 + l];
                const float2 c = Wr2[(k + 1) * 50 + l];
                const float2 d = Wr2[(k + 2) * 50 + l];
                const float2 e = Wr2[(k + 3) * 50 + l];
                u0 = fmaf(h4.x, a.x, u0); u1 = fmaf(h4.x, a.y, u1);
                u0 = fmaf(h4.y, c.x, u0); u1 = fmaf(h4.y, c.y, u1);
                u0 = fmaf(h4.z, d.x, u0); u1 = fmaf(h4.z, d.y, u1);
                u0 = fmaf(h4.w, e.x, u0); u1 = fmaf(h4.w, e.y, u1);
            }
#pragma unroll 5
            for (int k4 = 0; k4 < 25; ++k4) {
                const float4 n4 = n4p[k4];
                const int k = H_ + 4 * k4;
                const float2 a = Wr2[(k + 0) * 50 + l];
                const float2 c = Wr2[(k + 1) * 50 + l];
                const float2 d = Wr2[(k + 2) * 50 + l];
                const float2 e = Wr2[(k + 3) * 50 + l];
                u0 = fmaf(n4.x, a.x, u0); u1 = fmaf(n4.x, a.y, u1);
                u0 = fmaf(n4.y, c.x, u0); u1 = fmaf(n4.y, c.y, u1);
                u0 = fmaf(n4.z, d.x, u0); u1 = fmaf(n4.z, d.y, u1);
                u0 = fmaf(n4.w, e.x, u0); u1 = fmaf(n4.w, e.y, u1);
            }
            atomicAdd(out + b * H_ + 2 * l,     nm * fmaxf(u0, 0.f));
            atomicAdd(out + b * H_ + 2 * l + 1, nm * fmaxf(u1, 0.f));
        }
    }
}

// ---------------------------------------------------------------------------
extern "C" void kernel_launch(void* const* d_in, const int* in_sizes, int n_in,
                              void* d_out, int out_size, void* d_ws, size_t ws_size,
                              hipStream_t stream) {
    const float* nodes = (const float*)d_in[0];
    const float* edges = (const float*)d_in[1];
    const float* Wv    = (const float*)d_in[2];
    const float* Ww    = (const float*)d_in[3];
    const float* We    = (const float*)d_in[4];
    const float* Wu    = (const float*)d_in[5];
    const float* Wr    = (const float*)d_in[6];
    float* out = (float*)d_out;

    float* hidden = (float*)d_ws;     // RH
    float* hv     = hidden + RH;      // RH
    float* hwA    = hv + RH;          // RH
    float* hwB    = hwA + RH;         // RH

    hipMemsetAsync(d_out, 0, (size_t)out_size * sizeof(float), stream);

    const int grid = ROWS / NW;       // 1024 blocks, 4 blocks/CU
    k_proj0<<<grid, 256, 0, stream>>>(nodes, Wv, Ww, hv, hwA);

    k_pass<<<grid, 256, 0, stream>>>(edges, We, Wu, Wv, Ww, Wr, nodes,
                                     hv, hwA, hwB, nodes, hidden, out, 1);
    k_pass<<<grid, 256, 0, stream>>>(edges, We, Wu, Wv, Ww, Wr, nodes,
                                     hv, hwB, hwA, hidden, hidden, out, 1);
    k_pass<<<grid, 256, 0, stream>>>(edges, We, Wu, Wv, Ww, Wr, nodes,
                                     hv, hwA, hwB, hidden, hidden, out, 2);
}

// Round 8
// 196.279 us; speedup vs baseline: 1.5315x; 1.5315x over previous
//
#include <hip/hip_runtime.h>
#include <math.h>

#define B_   32
#define N_   128
#define H_   100
#define ROWS (B_ * N_)    // 4096
#define RH   (ROWS * H_)  // 409600

// ---------------------------------------------------------------------------
// K1: hv = nodes@Wv, hw = nodes@Ww. 2 rows per 256-thread block; lane j = h.
__global__ __launch_bounds__(256, 6) void k_proj0(const float* __restrict__ nodes,
                                                  const float* __restrict__ Wv,
                                                  const float* __restrict__ Ww,
                                                  float* __restrict__ hv,
                                                  float* __restrict__ hw) {
    __shared__ float nod_s[2][H_];
    const int row0 = blockIdx.x * 2;
    const int t = threadIdx.x, r = t >> 7, j = t & 127;
    {
        const float4* ng = (const float4*)(nodes + (size_t)row0 * H_);
        if (t < 50) ((float4*)nod_s)[t] = ng[t];
    }
    __syncthreads();
    if (j >= H_) return;
    const float4* h4p = (const float4*)nod_s[r];
    float va = 0.f, wa = 0.f;
#pragma unroll 5
    for (int k4 = 0; k4 < 25; ++k4) {
        const float4 h4 = h4p[k4];
        const int k = k4 * 4;
        va = fmaf(h4.x, Wv[(k + 0) * H_ + j], va);
        wa = fmaf(h4.x, Ww[(k + 0) * H_ + j], wa);
        va = fmaf(h4.y, Wv[(k + 1) * H_ + j], va);
        wa = fmaf(h4.y, Ww[(k + 1) * H_ + j], wa);
        va = fmaf(h4.z, Wv[(k + 2) * H_ + j], va);
        wa = fmaf(h4.z, Ww[(k + 2) * H_ + j], wa);
        va = fmaf(h4.w, Wv[(k + 3) * H_ + j], va);
        wa = fmaf(h4.w, Ww[(k + 3) * H_ + j], wa);
    }
    hv[(size_t)(row0 + r) * H_ + j] = va;
    hw[(size_t)(row0 + r) * H_ + j] = wa;
}

// ---------------------------------------------------------------------------
// K2: one fused message pass (r5 skeleton). 2 rows per 256-thread block
// (r = t>>7, j = t&127, lane j = h). Message loop: e_s b128 broadcast +
// m_s b32 broadcast from LDS, hw coalesced scalar from global. Mask and
// node-mask computed at stage time (shuffle-reduce). Then tanh update;
// mode 1 -> next-pass hv/hw projections; mode 2 -> fused readout.
__global__ __launch_bounds__(256, 6) void k_pass(const float* __restrict__ edges,
                                                 const float* __restrict__ We,
                                                 const float* __restrict__ Wu,
                                                 const float* __restrict__ Wv,
                                                 const float* __restrict__ Ww,
                                                 const float* __restrict__ Wr,
                                                 const float* __restrict__ nodes,
                                                 float* __restrict__ hv_io,
                                                 const float* __restrict__ hw_in,
                                                 float* __restrict__ hw_out,
                                                 const float* __restrict__ hid_in,
                                                 float* __restrict__ hidden,
                                                 float* __restrict__ out,
                                                 int mode) {
    __shared__ float4 e_s[2][N_];      // 4 KB
    __shared__ float  m_s[2][N_];      // 1 KB
    __shared__ float  asum_part[4];    // per-wave partial row sums
    __shared__ float  hid_s[2][H_];
    __shared__ float  msg_s[2][H_];
    __shared__ float  hn_s[2][H_];
    __shared__ float  nod_s[2][H_];    // mode 2 only
    __shared__ float  red_s[2][H_];    // mode 2 only

    const int row0 = blockIdx.x * 2;
    const int b = row0 >> 7;
    const int t = threadIdx.x, r = t >> 7, j = t & 127;
    const int wv = t >> 6, lane = t & 63;
    const int row = row0 + r;
    const bool act = (j < H_);

    {   // stage both rows' edges + mask; shuffle-reduce adjacency row sums
        const float4* eg = (const float4*)(edges + (size_t)row0 * N_ * 4);
        const float4 e = eg[t];                   // t == r*128 + j, coalesced
        e_s[r][j] = e;
        float s = (e.x + e.y) + (e.z + e.w);
        m_s[r][j] = (s != 0.f) ? 1.f : 0.f;
#pragma unroll
        for (int off = 32; off > 0; off >>= 1) s += __shfl_down(s, off);
        if (lane == 0) asum_part[wv] = s;
    }
    {   // stage pre-update hidden rows (50 float4); nodes too if readout pass
        const float4* hg = (const float4*)(hid_in + (size_t)row0 * H_);
        if (t < 50) ((float4*)hid_s)[t] = hg[t];
        if (mode == 2) {
            const float4* ng = (const float4*)(nodes + (size_t)row0 * H_);
            if (t < 50) ((float4*)nod_s)[t] = ng[t];
        }
    }
    __syncthreads();

    const float nm = ((asum_part[2 * r] + asum_part[2 * r + 1]) != 0.f) ? 1.f : 0.f;

    if (act) {
        const float hvv = hv_io[(size_t)row * H_ + j];
        const float we0 = We[0 * H_ + j], we1 = We[1 * H_ + j];
        const float we2 = We[2 * H_ + j], we3 = We[3 * H_ + j];
        const float* hwp = hw_in + (size_t)b * N_ * H_ + j;
        float acc = 0.f;
#pragma unroll 8
        for (int w = 0; w < N_; ++w) {
            const float4 e = e_s[r][w];           // LDS b128 broadcast
            const float  m = m_s[r][w];           // LDS b32 broadcast
            const float  hww = hwp[w * H_];       // coalesced 400B/wave-pair
            float p = hvv + hww;
            p = fmaf(e.x, we0, p);
            p = fmaf(e.y, we1, p);
            p = fmaf(e.z, we2, p);
            p = fmaf(e.w, we3, p);
            acc = fmaf(m, fmaxf(p, 0.f), acc);
        }
        msg_s[r][j] = acc;
    }
    __syncthreads();

    if (act) {
        const float4* h4p = (const float4*)hid_s[r];
        const float4* m4p = (const float4*)msg_s[r];
        float u = 0.f;
#pragma unroll 5
        for (int k4 = 0; k4 < 25; ++k4) {
            const float4 h4 = h4p[k4];
            const int k = k4 * 4;
            u = fmaf(h4.x, Wu[(k + 0) * H_ + j], u);
            u = fmaf(h4.y, Wu[(k + 1) * H_ + j], u);
            u = fmaf(h4.z, Wu[(k + 2) * H_ + j], u);
            u = fmaf(h4.w, Wu[(k + 3) * H_ + j], u);
        }
#pragma unroll 5
        for (int k4 = 0; k4 < 25; ++k4) {
            const float4 m4 = m4p[k4];
            const int k = H_ + k4 * 4;
            u = fmaf(m4.x, Wu[(k + 0) * H_ + j], u);
            u = fmaf(m4.y, Wu[(k + 1) * H_ + j], u);
            u = fmaf(m4.z, Wu[(k + 2) * H_ + j], u);
            u = fmaf(m4.w, Wu[(k + 3) * H_ + j], u);
        }
        const float nh = (nm != 0.f) ? tanhf(u) : hid_s[r][j];
        hn_s[r][j] = nh;
        if (mode == 1) hidden[(size_t)row * H_ + j] = nh;
    }
    __syncthreads();

    if (mode == 1) {        // next pass's hv/hw from fresh hidden (own rows)
        if (act) {
            const float4* h4p = (const float4*)hn_s[r];
            float va = 0.f, wa = 0.f;
#pragma unroll 5
            for (int k4 = 0; k4 < 25; ++k4) {
                const float4 h4 = h4p[k4];
                const int k = k4 * 4;
                va = fmaf(h4.x, Wv[(k + 0) * H_ + j], va);
                wa = fmaf(h4.x, Ww[(k + 0) * H_ + j], wa);
                va = fmaf(h4.y, Wv[(k + 1) * H_ + j], va);
                wa = fmaf(h4.y, Ww[(k + 1) * H_ + j], wa);
                va = fmaf(h4.z, Wv[(k + 2) * H_ + j], va);
                wa = fmaf(h4.z, Ww[(k + 2) * H_ + j], wa);
                va = fmaf(h4.w, Wv[(k + 3) * H_ + j], va);
                wa = fmaf(h4.w, Ww[(k + 3) * H_ + j], wa);
            }
            hv_io[(size_t)row * H_ + j] = va;     // row-local: safe in-place
            hw_out[(size_t)row * H_ + j] = wa;    // double-buffered
        }
    } else {                // mode 2: fused readout
        if (act) {
            const float4* h4p = (const float4*)hn_s[r];
            const float4* n4p = (const float4*)nod_s[r];
            float u = 0.f;
#pragma unroll 5
            for (int k4 = 0; k4 < 25; ++k4) {
                const float4 h4 = h4p[k4];
                const int k = k4 * 4;
                u = fmaf(h4.x, Wr[(k + 0) * H_ + j], u);
                u = fmaf(h4.y, Wr[(k + 1) * H_ + j], u);
                u = fmaf(h4.z, Wr[(k + 2) * H_ + j], u);
                u = fmaf(h4.w, Wr[(k + 3) * H_ + j], u);
            }
#pragma unroll 5
            for (int k4 = 0; k4 < 25; ++k4) {
                const float4 n4 = n4p[k4];
                const int k = H_ + k4 * 4;
                u = fmaf(n4.x, Wr[(k + 0) * H_ + j], u);
                u = fmaf(n4.y, Wr[(k + 1) * H_ + j], u);
                u = fmaf(n4.z, Wr[(k + 2) * H_ + j], u);
                u = fmaf(n4.w, Wr[(k + 3) * H_ + j], u);
            }
            red_s[r][j] = nm * fmaxf(u, 0.f);
        }
        __syncthreads();
        if (t < H_) atomicAdd(out + b * H_ + t, red_s[0][t] + red_s[1][t]);
    }
}

// ---------------------------------------------------------------------------
extern "C" void kernel_launch(void* const* d_in, const int* in_sizes, int n_in,
                              void* d_out, int out_size, void* d_ws, size_t ws_size,
                              hipStream_t stream) {
    const float* nodes = (const float*)d_in[0];
    const float* edges = (const float*)d_in[1];
    const float* Wv    = (const float*)d_in[2];
    const float* Ww    = (const float*)d_in[3];
    const float* We    = (const float*)d_in[4];
    const float* Wu    = (const float*)d_in[5];
    const float* Wr    = (const float*)d_in[6];
    float* out = (float*)d_out;

    float* hidden = (float*)d_ws;     // RH
    float* hv     = hidden + RH;      // RH
    float* hwA    = hv + RH;          // RH
    float* hwB    = hwA + RH;         // RH

    hipMemsetAsync(d_out, 0, (size_t)out_size * sizeof(float), stream);

    k_proj0<<<ROWS / 2, 256, 0, stream>>>(nodes, Wv, Ww, hv, hwA);

    k_pass<<<ROWS / 2, 256, 0, stream>>>(edges, We, Wu, Wv, Ww, Wr, nodes,
                                         hv, hwA, hwB, nodes, hidden, out, 1);
    k_pass<<<ROWS / 2, 256, 0, stream>>>(edges, We, Wu, Wv, Ww, Wr, nodes,
                                         hv, hwB, hwA, hidden, hidden, out, 1);
    k_pass<<<ROWS / 2, 256, 0, stream>>>(edges, We, Wu, Wv, Ww, Wr, nodes,
                                         hv, hwA, hwB, hidden, hidden, out, 2);
}